// Round 1
// 69.613 us; speedup vs baseline: 1.0083x; 1.0083x over previous
//
#include <hip/hip_runtime.h>

namespace {

constexpr int kN = 64;               // rows per (s,p) block
constexpr int kF4 = 32;              // 32 float4 per row (D=128)
constexpr int kStride = kF4 + 1;     // 33 float4 stride: 132 floats ≡ 4 mod 32 banks -> ≤2-way aliasing
constexpr int kRows = 32;            // tile edge: 32 x-rows and 32 y-rows per block

// Grid: 512 blocks = (s,p) * 2 x-halves * 2 y-halves  -> 2 blocks/CU, 2 waves/SIMD.
// Previous version used 256 blocks (1 wave/SIMD) and was latency-bound ~5x above
// its VALU/LDS throughput floor.
__global__ __launch_bounds__(256, 2)
void vcmp_kernel(const float* __restrict__ x, const float* __restrict__ y,
                 float* __restrict__ out) {
  __shared__ float4 xs[kRows * kStride];   // 32 rows of x, padded (16.9 KB)
  __shared__ float4 ys[kRows * kStride];   // 32 rows of y, padded (16.9 KB)
  __shared__ float xn2[kRows], xrn[kRows];
  __shared__ float yn2[kRows], yrn[kRows];

  const int tid = threadIdx.x;
  const int bid = blockIdx.x;          // 0..511
  const int sp  = bid >> 2;            // (s,p) flat index, 0..127
  const int xr0 = ((bid >> 1) & 1) << 5;  // x-row base: 0 or 32
  const int yr0 = (bid & 1) << 5;         // y-row base: 0 or 32

  // ---- global -> LDS staging (coalesced float4; 4 iters each) ----
  const float4* gx = reinterpret_cast<const float4*>(x) + ((size_t)sp * kN + xr0) * kF4;
  const float4* gy = reinterpret_cast<const float4*>(y) + ((size_t)sp * kN + yr0) * kF4;

  #pragma unroll
  for (int i = tid; i < kRows * kF4; i += 256) {
    xs[(i >> 5) * kStride + (i & 31)] = gx[i];
  }
  #pragma unroll
  for (int i = tid; i < kRows * kF4; i += 256) {
    ys[(i >> 5) * kStride + (i & 31)] = gy[i];
  }
  __syncthreads();

  // ---- per-row squared norms: 64 rows, 4 lanes per row, shfl-reduce ----
  {
    const int row  = tid >> 2;          // 0..63
    const int part = tid & 3;           // 0..3 -> 8 float4 chunks each
    const float4* src = (row < kRows) ? (xs + row * kStride)
                                      : (ys + (row - kRows) * kStride);
    float s = 0.f;
    #pragma unroll
    for (int c = 0; c < 8; ++c) {
      const float4 v = src[part * 8 + c];
      s = fmaf(v.x, v.x, s); s = fmaf(v.y, v.y, s);
      s = fmaf(v.z, v.z, s); s = fmaf(v.w, v.w, s);
    }
    s += __shfl_xor(s, 1);
    s += __shfl_xor(s, 2);
    if (part == 0) {
      const float rn = 1.f / fmaxf(sqrtf(s), 1e-12f);   // matches normalize eps
      if (row < kRows) { xn2[row] = s;         xrn[row] = rn; }
      else             { yn2[row - kRows] = s; yrn[row - kRows] = rn; }
    }
  }
  __syncthreads();

  // ---- main: thread (tn, tm): rows 2*tn+{0,1}, cols tm, tm+16 ----
  const int tn = tid >> 4;   // 0..15
  const int tm = tid & 15;   // 0..15
  const int n0 = tn << 1;    // local x-row pair base

  const float4* __restrict__ xa0 = xs + n0 * kStride;
  const float4* __restrict__ xa1 = xa0 + kStride;
  const float4* __restrict__ yb0 = ys + tm * kStride;
  const float4* __restrict__ yb1 = ys + (tm + 16) * kStride;

  float dot00 = 0.f, dot01 = 0.f, dot10 = 0.f, dot11 = 0.f;
  float l1_00 = 0.f, l1_01 = 0.f, l1_10 = 0.f, l1_11 = 0.f;

  #pragma unroll 8
  for (int c = 0; c < kF4; ++c) {
    const float4 a0 = xa0[c];   // broadcast to 16 lanes, banks 8*tn: conflict-free
    const float4 a1 = xa1[c];
    const float4 b0 = yb0[c];   // 16 distinct rows, <=2-way aliasing (free)
    const float4 b1 = yb1[c];

    dot00 = fmaf(a0.x, b0.x, dot00); dot00 = fmaf(a0.y, b0.y, dot00);
    dot00 = fmaf(a0.z, b0.z, dot00); dot00 = fmaf(a0.w, b0.w, dot00);
    dot01 = fmaf(a0.x, b1.x, dot01); dot01 = fmaf(a0.y, b1.y, dot01);
    dot01 = fmaf(a0.z, b1.z, dot01); dot01 = fmaf(a0.w, b1.w, dot01);
    dot10 = fmaf(a1.x, b0.x, dot10); dot10 = fmaf(a1.y, b0.y, dot10);
    dot10 = fmaf(a1.z, b0.z, dot10); dot10 = fmaf(a1.w, b0.w, dot10);
    dot11 = fmaf(a1.x, b1.x, dot11); dot11 = fmaf(a1.y, b1.y, dot11);
    dot11 = fmaf(a1.z, b1.z, dot11); dot11 = fmaf(a1.w, b1.w, dot11);

    l1_00 += fabsf(a0.x - b0.x); l1_00 += fabsf(a0.y - b0.y);
    l1_00 += fabsf(a0.z - b0.z); l1_00 += fabsf(a0.w - b0.w);
    l1_01 += fabsf(a0.x - b1.x); l1_01 += fabsf(a0.y - b1.y);
    l1_01 += fabsf(a0.z - b1.z); l1_01 += fabsf(a0.w - b1.w);
    l1_10 += fabsf(a1.x - b0.x); l1_10 += fabsf(a1.y - b0.y);
    l1_10 += fabsf(a1.z - b0.z); l1_10 += fabsf(a1.w - b0.w);
    l1_11 += fabsf(a1.x - b1.x); l1_11 += fabsf(a1.y - b1.y);
    l1_11 += fabsf(a1.z - b1.z); l1_11 += fabsf(a1.w - b1.w);
  }

  // ---- epilogue: cos = dot*rnx*rny, l2 = sqrt(nx2 + ny2 - 2 dot), l1 ----
  const float nx2_0 = xn2[n0],     rnx_0 = xrn[n0];
  const float nx2_1 = xn2[n0 + 1], rnx_1 = xrn[n0 + 1];
  const float ny2_0 = yn2[tm],      rny_0 = yrn[tm];
  const float ny2_1 = yn2[tm + 16], rny_1 = yrn[tm + 16];

  float* orow0 = out + ((size_t)(sp * kN + xr0 + n0) * kN + yr0) * 3;
  float* orow1 = orow0 + (size_t)kN * 3;

  float3 v;
  v.x = dot00 * rnx_0 * rny_0;
  v.y = sqrtf(fmaxf(nx2_0 + ny2_0 - 2.f * dot00, 0.f));
  v.z = l1_00;
  *reinterpret_cast<float3*>(orow0 + (size_t)tm * 3) = v;

  v.x = dot01 * rnx_0 * rny_1;
  v.y = sqrtf(fmaxf(nx2_0 + ny2_1 - 2.f * dot01, 0.f));
  v.z = l1_01;
  *reinterpret_cast<float3*>(orow0 + (size_t)(tm + 16) * 3) = v;

  v.x = dot10 * rnx_1 * rny_0;
  v.y = sqrtf(fmaxf(nx2_1 + ny2_0 - 2.f * dot10, 0.f));
  v.z = l1_10;
  *reinterpret_cast<float3*>(orow1 + (size_t)tm * 3) = v;

  v.x = dot11 * rnx_1 * rny_1;
  v.y = sqrtf(fmaxf(nx2_1 + ny2_1 - 2.f * dot11, 0.f));
  v.z = l1_11;
  *reinterpret_cast<float3*>(orow1 + (size_t)(tm + 16) * 3) = v;
}

} // namespace

extern "C" void kernel_launch(void* const* d_in, const int* in_sizes, int n_in,
                              void* d_out, int out_size, void* d_ws, size_t ws_size,
                              hipStream_t stream) {
  const float* x = (const float*)d_in[0];
  const float* y = (const float*)d_in[1];
  float* out = (float*)d_out;
  vcmp_kernel<<<dim3(512), dim3(256), 0, stream>>>(x, y, out);
}